// Round 5
// baseline (283.114 us; speedup 1.0000x reference)
//
#include <hip/hip_runtime.h>
#include <math.h>

#define SS 512
#define DD 128
#define HH 4
#define DHH 32
#define DFF 512
#define E_EDGES 261632   // S*S - S

// exact gelu (backbone)
__device__ __forceinline__ float gelu_f(float v) {
    return 0.5f * v * (1.0f + erff(v * 0.70710678118654752f));
}
// fast gelu (edge kernel): x * sigmoid(1.5957691*(x + 0.044715 x^3))
__device__ __forceinline__ float fgelu(float x) {
    float x2 = x * x;
    float z = x * fmaf(-0.0713548164f, x2, -1.5957691216f);
    float e = __expf(z);
    return x * __builtin_amdgcn_rcpf(1.0f + e);
}

// ---------------- qkv projection (optionally fused embedding) ----------------
template<int DO_EMBED>
__global__ __launch_bounds__(384) void k_qkv(const float* __restrict__ xin,
                                             const int* __restrict__ tok,
                                             const float* __restrict__ emb,
                                             float* __restrict__ xout,
                                             const float* __restrict__ W,
                                             const float* __restrict__ b,
                                             float* __restrict__ qkv) {
    __shared__ float xs[2][DD];
    int r0 = blockIdx.x * 2;
    int c = threadIdx.x;
    if (DO_EMBED) {
        if (c < 256) {                              // embed rows r0, r0+1
            int row = r0 + (c >> 7), d = c & 127;
            float v = emb[(size_t)tok[row] * DD + d];
            int i2 = (d >> 1) << 1;
            float div = expf(-(float)i2 * (9.210340371976184f / 128.0f));
            float arg = (float)row * div;
            v += (d & 1) ? cosf(arg) : sinf(arg);
            xs[c >> 7][d] = v;
            xout[row * DD + d] = v;                 // residual for tail-l0
        }
    } else {
        if (c < 256) xs[c >> 7][c & 127] = xin[r0 * DD + c];
    }
    __syncthreads();
    float a0 = 0, a1 = 0;
    for (int d = 0; d < DD; ++d) {
        float w = W[d * 384 + c];
        a0 += xs[0][d] * w; a1 += xs[1][d] * w;
    }
    float bb = b[c];
    qkv[(r0 + 0) * 384 + c] = a0 + bb;
    qkv[(r0 + 1) * 384 + c] = a1 + bb;
}

// ---------------- fused attention + layer tail (+ optional node projections) ----------------
// 2 query rows per block (rows 2b, 2b+1); o stays in LDS.
template<int DO_NODE>
__global__ __launch_bounds__(256) void k_attn_tail(const float* __restrict__ qkv,
                                                   float* __restrict__ x,
                                                   const float* __restrict__ Wo,
                                                   const float* __restrict__ bo,
                                                   const float* __restrict__ g1,
                                                   const float* __restrict__ b1,
                                                   const float* __restrict__ W1,
                                                   const float* __restrict__ bf1,
                                                   const float* __restrict__ W2,
                                                   const float* __restrict__ bf2,
                                                   const float* __restrict__ g2,
                                                   const float* __restrict__ b2,
                                                   const float* __restrict__ nodeW,
                                                   const float* __restrict__ nodeb,
                                                   const float* __restrict__ scW1,
                                                   const float* __restrict__ scb1,
                                                   const float* __restrict__ teW,
                                                   const float* __restrict__ teb,
                                                   float* __restrict__ out_node,
                                                   float* __restrict__ As,
                                                   float* __restrict__ Atp,
                                                   float* __restrict__ Bs,
                                                   float* __restrict__ Btp) {
    int r0 = blockIdx.x * 2;
    int q0 = r0, q1 = r0 + 1;
    int tid = threadIdx.x;
    int h = tid >> 6, lane = tid & 63;
    __shared__ float sq[2][DD];
    __shared__ float ps[2][HH][SS];
    __shared__ float tile[64 * 129];
    __shared__ float os[2][DD];
    __shared__ float x1[2][DD];
    __shared__ float hh[2][DFF];
    __shared__ float xf[2][DD];
    __shared__ float red[2][2];
    if (tid < 128) {
        sq[0][tid] = qkv[q0 * 384 + tid];
        sq[1][tid] = qkv[q1 * 384 + tid];
    }
    const float scale = 0.17677669529663687f;       // 1/sqrt(32)
    float sc0[8], sc1[8];
    float m0 = -1e30f, m1 = -1e30f;
    for (int kk = 0; kk < 8; ++kk) {
        __syncthreads();                            // protects tile (and sq on first iter)
        for (int i = tid * 4; i < 64 * 128; i += 1024) {
            int r = i >> 7, c = i & 127;
            const float4 v = *reinterpret_cast<const float4*>(&qkv[(kk * 64 + r) * 384 + 128 + c]);
            tile[r * 129 + c + 0] = v.x;
            tile[r * 129 + c + 1] = v.y;
            tile[r * 129 + c + 2] = v.z;
            tile[r * 129 + c + 3] = v.w;
        }
        __syncthreads();
        float a0 = 0.f, a1 = 0.f;
        #pragma unroll
        for (int d = 0; d < DHH; ++d) {
            float kv = tile[lane * 129 + h * DHH + d];
            a0 += sq[0][h * DHH + d] * kv;
            a1 += sq[1][h * DHH + d] * kv;
        }
        sc0[kk] = a0 * scale; sc1[kk] = a1 * scale;
        m0 = fmaxf(m0, sc0[kk]); m1 = fmaxf(m1, sc1[kk]);
    }
    for (int off = 32; off; off >>= 1) {
        m0 = fmaxf(m0, __shfl_xor(m0, off));
        m1 = fmaxf(m1, __shfl_xor(m1, off));
    }
    float s0 = 0.f, s1 = 0.f;
    for (int kk = 0; kk < 8; ++kk) {
        sc0[kk] = __expf(sc0[kk] - m0); s0 += sc0[kk];
        sc1[kk] = __expf(sc1[kk] - m1); s1 += sc1[kk];
    }
    for (int off = 32; off; off >>= 1) {
        s0 += __shfl_xor(s0, off);
        s1 += __shfl_xor(s1, off);
    }
    float i0 = 1.0f / s0, i1 = 1.0f / s1;
    for (int kk = 0; kk < 8; ++kk) {
        ps[0][h][kk * 64 + lane] = sc0[kk] * i0;
        ps[1][h][kk * 64 + lane] = sc1[kk] * i1;
    }
    // PV: restage V tiles into LDS
    int d = lane & 31, hh2 = lane >> 5;
    float a0 = 0.f, a1 = 0.f;
    for (int kk = 0; kk < 8; ++kk) {
        __syncthreads();                            // prior tile reads done (incl. ps-write sync on kk=0)
        for (int i = tid * 4; i < 64 * 128; i += 1024) {
            int r = i >> 7, c = i & 127;
            const float4 v = *reinterpret_cast<const float4*>(&qkv[(kk * 64 + r) * 384 + 256 + c]);
            tile[r * 129 + c + 0] = v.x;
            tile[r * 129 + c + 1] = v.y;
            tile[r * 129 + c + 2] = v.z;
            tile[r * 129 + c + 3] = v.w;
        }
        __syncthreads();
        #pragma unroll
        for (int i = 0; i < 32; ++i) {
            int key = hh2 * 32 + i;
            float v = tile[key * 129 + h * DHH + d];
            a0 += ps[0][h][kk * 64 + key] * v;
            a1 += ps[1][h][kk * 64 + key] * v;
        }
    }
    a0 += __shfl_down(a0, 32);
    a1 += __shfl_down(a1, 32);
    if (lane < 32) {
        os[0][h * DHH + d] = a0;
        os[1][h * DHH + d] = a1;
    }
    __syncthreads();
    // ---- tail: proj + LN1 + FFN1 + FFN2 + LN2 ----
    int grp = tid >> 7, c = tid & 127;
    int wig = (tid >> 6) & 1;
    float acc = 0.f;
    for (int dd = 0; dd < DD; ++dd) acc += os[grp][dd] * Wo[dd * DD + c];
    float val = x[(r0 + grp) * DD + c] + acc + bo[c];
    float sum = val;
    for (int off = 32; off; off >>= 1) sum += __shfl_xor(sum, off);
    if ((tid & 63) == 0) red[grp][wig] = sum;
    __syncthreads();
    float mean = (red[grp][0] + red[grp][1]) * (1.0f / 128.0f);
    float dv = val - mean;
    float sqv = dv * dv;
    for (int off = 32; off; off >>= 1) sqv += __shfl_xor(sqv, off);
    __syncthreads();
    if ((tid & 63) == 0) red[grp][wig] = sqv;
    __syncthreads();
    float var = (red[grp][0] + red[grp][1]) * (1.0f / 128.0f);
    float xv = dv * rsqrtf(var + 1e-5f) * g1[c] + b1[c];
    x1[grp][c] = xv;
    __syncthreads();
    {
        int c0 = tid, c1 = tid + 256;
        float s00 = 0, s01 = 0, s10 = 0, s11 = 0;
        for (int dd = 0; dd < DD; ++dd) {
            float xa = x1[0][dd], xb = x1[1][dd];
            float w0 = W1[dd * DFF + c0], w1 = W1[dd * DFF + c1];
            s00 = fmaf(xa, w0, s00); s10 = fmaf(xb, w0, s10);
            s01 = fmaf(xa, w1, s01); s11 = fmaf(xb, w1, s11);
        }
        hh[0][c0] = gelu_f(s00 + bf1[c0]);
        hh[1][c0] = gelu_f(s10 + bf1[c0]);
        hh[0][c1] = gelu_f(s01 + bf1[c1]);
        hh[1][c1] = gelu_f(s11 + bf1[c1]);
    }
    __syncthreads();
    float acc2 = 0.f;
    for (int dd = 0; dd < DFF; ++dd) acc2 += hh[grp][dd] * W2[dd * DD + c];
    float val2 = x1[grp][c] + acc2 + bf2[c];
    float sum2 = val2;
    for (int off = 32; off; off >>= 1) sum2 += __shfl_xor(sum2, off);
    if ((tid & 63) == 0) red[grp][wig] = sum2;
    __syncthreads();
    float mean2 = (red[grp][0] + red[grp][1]) * (1.0f / 128.0f);
    float dv2 = val2 - mean2;
    float sq2 = dv2 * dv2;
    for (int off = 32; off; off >>= 1) sq2 += __shfl_xor(sq2, off);
    __syncthreads();
    if ((tid & 63) == 0) red[grp][wig] = sq2;
    __syncthreads();
    float var2 = (red[grp][0] + red[grp][1]) * (1.0f / 128.0f);
    float outv = dv2 * rsqrtf(var2 + 1e-5f) * g2[c] + b2[c];
    if (!DO_NODE) {
        x[(r0 + grp) * DD + c] = outv;
        return;
    }
    // ---- fused node projections (row-local; x never leaves the block) ----
    xf[grp][c] = outv;
    __syncthreads();
    for (int c0 = tid; c0 < 896; c0 += 256) {
        int rl = (c0 >= 448) ? 1 : 0;
        int cc = c0 - rl * 448;
        int row = r0 + rl;
        const float* wp; int ldw; float bias = 0.f;
        if (cc < 64)       { wp = nodeW + cc;                     ldw = 64;  bias = nodeb[cc]; }
        else if (cc < 192) { wp = scW1 + (cc - 64);               ldw = 128; bias = scb1[cc - 64]; }
        else if (cc < 320) { wp = scW1 + 128 * 128 + (cc - 192);  ldw = 128; }
        else if (cc < 384) { wp = teW + (cc - 320);               ldw = 64;  bias = teb[cc - 320]; }
        else               { wp = teW + 128 * 64 + (cc - 384);    ldw = 64;  }
        float a = bias;
        for (int dd = 0; dd < DD; ++dd) a += xf[rl][dd] * wp[dd * ldw];
        if (cc < 64)       out_node[row * 64 + cc] = a;
        else if (cc < 192) As[row * 128 + (cc - 64)] = a;
        else if (cc < 320) {
            int j0 = cc - 192;
            int hhi = j0 >> 6, rem = j0 & 63, jj = rem & 15, k = rem >> 4;
            Atp[row * 128 + jj * 8 + k * 2 + hhi] = a;
        }
        else if (cc < 384) Bs[row * 64 + (cc - 320)] = a;
        else {
            int jf = cc - 384, jj = jf & 15, k = jf >> 4;
            Btp[row * 64 + jj * 4 + k] = a;
        }
    }
}

// ---------------- edge kernel: 4 edges per wave (16 lanes each); gumbel + edge_index inline ----------------
__global__ __launch_bounds__(256) void k_edges(const float* __restrict__ As,
                                               const float* __restrict__ Atp,
                                               const float* __restrict__ Bs,
                                               const float* __restrict__ Btp,
                                               const float* __restrict__ scW1,
                                               const float* __restrict__ scW2,
                                               const float* __restrict__ scb2p,
                                               const float* __restrict__ teW,
                                               const float* __restrict__ u,
                                               float* __restrict__ out_feat,
                                               float* __restrict__ out_gate,
                                               float* __restrict__ out_ei) {
    int s = blockIdx.x;
    int seg = blockIdx.y;                           // 0..1
    __shared__ float lAs[128], lap[128], lw2[128], lBs[64], lbp[64];
    int tid = threadIdx.x;
    if (tid < 128) {
        lAs[tid] = As[s * 128 + tid];
        lap[tid] = scW1[256 * 128 + tid];
        lw2[tid] = scW2[tid];
    } else if (tid < 192) {
        int j = tid - 128;
        lBs[j] = Bs[s * 64 + j];
        lbp[j] = teW[256 * 64 + j];
    }
    __syncthreads();
    int w = tid >> 6, lane = tid & 63;
    int g = lane >> 4, jj = lane & 15;
    float rAs[8], rap[8], rw2[8], rBs[4], rbp[4];
    #pragma unroll
    for (int k = 0; k < 4; ++k) {
        int j = jj + 16 * k;
        rAs[2 * k] = lAs[j]; rAs[2 * k + 1] = lAs[j + 64];
        rap[2 * k] = lap[j]; rap[2 * k + 1] = lap[j + 64];
        rw2[2 * k] = lw2[j]; rw2[2 * k + 1] = lw2[j + 64];
        rBs[k] = lBs[j]; rbp[k] = lbp[j];
    }
    float scb2 = scb2p[0];
    for (int iter = 0; iter < 16; ++iter) {
        int idx = seg * 256 + w * 64 + iter * 4 + g;
        if (idx >= 511) continue;                   // uniform per 16-lane group
        int t = idx + (idx >= s);
        int e = s * 511 + idx;
        float pd = (float)(s - t) * (1.0f / 512.0f);
        const float4* ap = reinterpret_cast<const float4*>(&Atp[(size_t)t * 128 + jj * 8]);
        float4 at0 = ap[0];
        float4 at1 = ap[1];
        float part, a;
        a = fmaf(pd, rap[0], rAs[0] + at0.x); part  = fgelu(a) * rw2[0];
        a = fmaf(pd, rap[1], rAs[1] + at0.y); part += fgelu(a) * rw2[1];
        a = fmaf(pd, rap[2], rAs[2] + at0.z); part += fgelu(a) * rw2[2];
        a = fmaf(pd, rap[3], rAs[3] + at0.w); part += fgelu(a) * rw2[3];
        a = fmaf(pd, rap[4], rAs[4] + at1.x); part += fgelu(a) * rw2[4];
        a = fmaf(pd, rap[5], rAs[5] + at1.y); part += fgelu(a) * rw2[5];
        a = fmaf(pd, rap[6], rAs[6] + at1.z); part += fgelu(a) * rw2[6];
        a = fmaf(pd, rap[7], rAs[7] + at1.w); part += fgelu(a) * rw2[7];
        part += __shfl_xor(part, 1);
        part += __shfl_xor(part, 2);
        part += __shfl_xor(part, 4);
        part += __shfl_xor(part, 8);
        float logit = part + scb2;
        float uu = fminf(fmaxf(u[e], 1e-8f), 1.0f - 1e-8f);
        float nlv = -__logf(uu);                    // gate = 1/(1 + nl*exp(-logit))
        float gate = __builtin_amdgcn_rcpf(1.0f + nlv * __expf(-logit));
        float4 bt = *reinterpret_cast<const float4*>(&Btp[(size_t)t * 64 + jj * 4]);
        float f0 = fmaf(pd, rbp[0], rBs[0] + bt.x) * gate;
        float f1 = fmaf(pd, rbp[1], rBs[1] + bt.y) * gate;
        float f2 = fmaf(pd, rbp[2], rBs[2] + bt.z) * gate;
        float f3 = fmaf(pd, rbp[3], rBs[3] + bt.w) * gate;
        size_t base = (size_t)e * 64 + jj;
        out_feat[base + 0]  = f0;
        out_feat[base + 16] = f1;
        out_feat[base + 32] = f2;
        out_feat[base + 48] = f3;
        if (jj == 0) { out_gate[e] = gate; out_ei[e] = (float)s; }
        else if (jj == 1) out_ei[E_EDGES + e] = (float)t;
    }
}

extern "C" void kernel_launch(void* const* d_in, const int* in_sizes, int n_in,
                              void* d_out, int out_size, void* d_ws, size_t ws_size,
                              hipStream_t stream) {
    const int*   tok   = (const int*)d_in[0];
    const float* u     = (const float*)d_in[1];
    const float* emb   = (const float*)d_in[2];
    const float* Wqkv  = (const float*)d_in[3];
    const float* bqkv  = (const float*)d_in[4];
    const float* Wo    = (const float*)d_in[5];
    const float* bo    = (const float*)d_in[6];
    const float* ln1g  = (const float*)d_in[7];
    const float* ln1b  = (const float*)d_in[8];
    const float* Wff1  = (const float*)d_in[9];
    const float* bff1  = (const float*)d_in[10];
    const float* Wff2  = (const float*)d_in[11];
    const float* bff2  = (const float*)d_in[12];
    const float* ln2g  = (const float*)d_in[13];
    const float* ln2b  = (const float*)d_in[14];
    const float* nodeW = (const float*)d_in[15];
    const float* nodeb = (const float*)d_in[16];
    const float* scW1  = (const float*)d_in[17];
    const float* scb1  = (const float*)d_in[18];
    const float* scW2  = (const float*)d_in[19];
    const float* scb2  = (const float*)d_in[20];
    const float* teW   = (const float*)d_in[21];
    const float* teb   = (const float*)d_in[22];

    float* out      = (float*)d_out;
    float* out_node = out;                                    // [512,64]
    float* out_feat = out + 512 * 64;                         // [E,64]
    float* out_ei   = out_feat + (size_t)E_EDGES * 64;        // [2,E]
    float* out_gate = out_ei + 2 * (size_t)E_EDGES;           // [E]

    float* ws   = (float*)d_ws;
    float* x    = ws;                                         // 512*128
    float* qkv  = x + 512 * 128;                              // 512*384
    float* As   = qkv + 512 * 384;                            // 512*128
    float* Atp  = As + 512 * 128;                             // 512*128
    float* Bs   = Atp + 512 * 128;                            // 512*64
    float* Btp  = Bs + 512 * 64;                              // 512*64

    // layer 0
    k_qkv<1><<<dim3(256), dim3(384), 0, stream>>>(nullptr, tok, emb, x,
                                                  Wqkv, bqkv, qkv);
    k_attn_tail<0><<<dim3(256), dim3(256), 0, stream>>>(qkv, x, Wo, bo,
                                                        ln1g, ln1b, Wff1, bff1, Wff2, bff2,
                                                        ln2g, ln2b,
                                                        nullptr, nullptr, nullptr, nullptr,
                                                        nullptr, nullptr,
                                                        nullptr, nullptr, nullptr, nullptr, nullptr);
    // layer 1
    k_qkv<0><<<dim3(256), dim3(384), 0, stream>>>(x, nullptr, nullptr, nullptr,
                                                  Wqkv + 128 * 384, bqkv + 384, qkv);
    k_attn_tail<1><<<dim3(256), dim3(256), 0, stream>>>(qkv, x, Wo + 128 * 128, bo + 128,
                                                        ln1g + 128, ln1b + 128,
                                                        Wff1 + 128 * 512, bff1 + 512,
                                                        Wff2 + 512 * 128, bff2 + 128,
                                                        ln2g + 128, ln2b + 128,
                                                        nodeW, nodeb, scW1, scb1, teW, teb,
                                                        out_node, As, Atp, Bs, Btp);
    k_edges<<<dim3(512, 2), dim3(256), 0, stream>>>(As, Atp, Bs, Btp, scW1, scW2, scb2, teW, u,
                                                    out_feat, out_gate, out_ei);
}

// Round 7
// 281.622 us; speedup vs baseline: 1.0053x; 1.0053x over previous
//
#include <hip/hip_runtime.h>
#include <math.h>

#define SS 512
#define DD 128
#define HH 4
#define DHH 32
#define DFF 512
#define E_EDGES 261632   // S*S - S

// exact gelu (backbone)
__device__ __forceinline__ float gelu_f(float v) {
    return 0.5f * v * (1.0f + erff(v * 0.70710678118654752f));
}
// fast gelu (edge kernel)
__device__ __forceinline__ float fgelu(float x) {
    float x2 = x * x;
    float z = x * fmaf(-0.0713548164f, x2, -1.5957691216f);
    float e = __expf(z);
    return x * __builtin_amdgcn_rcpf(1.0f + e);
}

// ---------------- qkv projection: 1 row/block, 512 blocks (optionally fused embedding) ----------------
template<int DO_EMBED>
__global__ __launch_bounds__(384) void k_qkv(const float* __restrict__ xin,
                                             const int* __restrict__ tok,
                                             const float* __restrict__ emb,
                                             float* __restrict__ xout,
                                             const float* __restrict__ W,
                                             const float* __restrict__ b,
                                             float* __restrict__ qkv) {
    __shared__ float xs[DD];
    int row = blockIdx.x;
    int c = threadIdx.x;
    if (DO_EMBED) {
        if (c < 128) {
            float v = emb[(size_t)tok[row] * DD + c];
            int i2 = (c >> 1) << 1;
            float div = expf(-(float)i2 * (9.210340371976184f / 128.0f));
            float arg = (float)row * div;
            v += (c & 1) ? cosf(arg) : sinf(arg);
            xs[c] = v;
            xout[row * DD + c] = v;                 // residual for tail-l0
        }
    } else {
        if (c < 128) xs[c] = xin[row * DD + c];
    }
    __syncthreads();
    float a = b[c];
    #pragma unroll 4
    for (int d = 0; d < DD; ++d) a = fmaf(xs[d], W[d * 384 + c], a);
    qkv[row * 384 + c] = a;
}

// ---------------- fused attention + layer tail, high occupancy ----------------
// 1024 threads (16 waves), 2 rows per block, 256 blocks.
template<int DO_NODE>
__global__ __launch_bounds__(1024) void k_attn_tail(const float* __restrict__ qkv,
                                                    float* __restrict__ x,
                                                    const float* __restrict__ Wo,
                                                    const float* __restrict__ bo,
                                                    const float* __restrict__ g1,
                                                    const float* __restrict__ b1,
                                                    const float* __restrict__ W1,
                                                    const float* __restrict__ bf1,
                                                    const float* __restrict__ W2,
                                                    const float* __restrict__ bf2,
                                                    const float* __restrict__ g2,
                                                    const float* __restrict__ b2,
                                                    const float* __restrict__ nodeW,
                                                    const float* __restrict__ nodeb,
                                                    const float* __restrict__ scW1,
                                                    const float* __restrict__ scb1,
                                                    const float* __restrict__ teW,
                                                    const float* __restrict__ teb,
                                                    float* __restrict__ out_node,
                                                    float* __restrict__ As,
                                                    float* __restrict__ Atp,
                                                    float* __restrict__ Bs,
                                                    float* __restrict__ Btp) {
    int r0 = blockIdx.x * 2;
    int tid = threadIdx.x;
    int wave = tid >> 6, lane = tid & 63;
    __shared__ float sq[2][DD];
    __shared__ float ps[2][HH][SS];                 // 16 KB
    __shared__ float smax[2][HH][4], ssum[2][HH][4];
    __shared__ float opart[2][HH][4][DHH];          // 4 KB
    __shared__ float os[2][DD];
    __shared__ float pred4[4][2][DD];               // 4 KB (split-K partials, reused)
    __shared__ float x1[2][DD];
    __shared__ float hhl[2][DFF];                   // 4 KB
    __shared__ float xf[2][DD];
    __shared__ float red[2][2];
    if (tid < 256) sq[tid >> 7][tid & 127] = qkv[(r0 + (tid >> 7)) * 384 + (tid & 127)];
    __syncthreads();
    // ---- QK^T: wave = (head h, key-quarter kh); lane: keys kh*128+lane, +64; both rows ----
    const float scale = 0.17677669529663687f;       // 1/sqrt(32)
    int h = wave & 3, kh = wave >> 2;
    int k0 = kh * 128 + lane, k1 = k0 + 64;
    float s00 = 0, s01 = 0, s10 = 0, s11 = 0;       // s[row][key]
    {
        const float4* kp0 = reinterpret_cast<const float4*>(&qkv[(size_t)k0 * 384 + 128 + h * DHH]);
        const float4* kp1 = reinterpret_cast<const float4*>(&qkv[(size_t)k1 * 384 + 128 + h * DHH]);
        #pragma unroll
        for (int i = 0; i < 8; ++i) {
            float4 a = kp0[i], bq = kp1[i];
            int d0 = h * DHH + i * 4;
            float q00 = sq[0][d0], q01 = sq[0][d0 + 1], q02 = sq[0][d0 + 2], q03 = sq[0][d0 + 3];
            float q10 = sq[1][d0], q11 = sq[1][d0 + 1], q12 = sq[1][d0 + 2], q13 = sq[1][d0 + 3];
            s00 += a.x * q00 + a.y * q01 + a.z * q02 + a.w * q03;
            s10 += a.x * q10 + a.y * q11 + a.z * q12 + a.w * q13;
            s01 += bq.x * q00 + bq.y * q01 + bq.z * q02 + bq.w * q03;
            s11 += bq.x * q10 + bq.y * q11 + bq.z * q12 + bq.w * q13;
        }
        s00 *= scale; s01 *= scale; s10 *= scale; s11 *= scale;
    }
    // ---- softmax across 4 waves per (row, head) ----
    float m0 = fmaxf(s00, s01), m1 = fmaxf(s10, s11);
    for (int off = 32; off; off >>= 1) {
        m0 = fmaxf(m0, __shfl_xor(m0, off));
        m1 = fmaxf(m1, __shfl_xor(m1, off));
    }
    if (lane == 0) { smax[0][h][kh] = m0; smax[1][h][kh] = m1; }
    __syncthreads();
    float M0 = fmaxf(fmaxf(smax[0][h][0], smax[0][h][1]), fmaxf(smax[0][h][2], smax[0][h][3]));
    float M1 = fmaxf(fmaxf(smax[1][h][0], smax[1][h][1]), fmaxf(smax[1][h][2], smax[1][h][3]));
    float e00 = __expf(s00 - M0), e01 = __expf(s01 - M0);
    float e10 = __expf(s10 - M1), e11 = __expf(s11 - M1);
    float l0 = e00 + e01, l1 = e10 + e11;
    for (int off = 32; off; off >>= 1) {
        l0 += __shfl_xor(l0, off);
        l1 += __shfl_xor(l1, off);
    }
    if (lane == 0) { ssum[0][h][kh] = l0; ssum[1][h][kh] = l1; }
    __syncthreads();
    float inv0 = 1.0f / (ssum[0][h][0] + ssum[0][h][1] + ssum[0][h][2] + ssum[0][h][3]);
    float inv1 = 1.0f / (ssum[1][h][0] + ssum[1][h][1] + ssum[1][h][2] + ssum[1][h][3]);
    ps[0][h][k0] = e00 * inv0; ps[0][h][k1] = e01 * inv0;
    ps[1][h][k0] = e10 * inv1; ps[1][h][k1] = e11 * inv1;
    __syncthreads();
    // ---- PV: wave = (head hp, row rp, key-half khalf); lane: d = lane&31, key-quarter sub ----
    {
        int hp = wave & 3, rp = (wave >> 2) & 1, khalf = wave >> 3;
        int d = lane & 31, sub = lane >> 5;
        int kbase = khalf * 256 + sub * 128;
        float acc = 0.f;
        #pragma unroll 4
        for (int i = 0; i < 128; ++i) {
            int ki = kbase + i;
            acc += ps[rp][hp][ki] * qkv[(size_t)ki * 384 + 256 + hp * DHH + d];
        }
        opart[rp][hp][khalf * 2 + sub][d] = acc;
    }
    __syncthreads();
    if (tid < 256) {
        int r = tid >> 7, cc = tid & 127;
        int h2 = cc >> 5, dd = cc & 31;
        os[r][cc] = opart[r][h2][0][dd] + opart[r][h2][1][dd] +
                    opart[r][h2][2][dd] + opart[r][h2][3][dd];
    }
    __syncthreads();
    // ---- proj (4-way split-K) ----
    int idx = tid & 255, kseg = tid >> 8;
    int rr = idx >> 7, cc2 = idx & 127;
    {
        float part = 0.f;
        #pragma unroll 8
        for (int q = 0; q < 32; ++q) {
            int dd = kseg * 32 + q;
            part = fmaf(os[rr][dd], Wo[dd * DD + cc2], part);
        }
        pred4[kseg][rr][cc2] = part;
    }
    __syncthreads();
    // ---- +residual, LN1 ----
    float val = pred4[0][rr][cc2] + pred4[1][rr][cc2] + pred4[2][rr][cc2] + pred4[3][rr][cc2]
              + x[(r0 + rr) * DD + cc2] + bo[cc2];
    int wig = (tid >> 6) & 1;
    float sum = val;
    for (int off = 32; off; off >>= 1) sum += __shfl_xor(sum, off);
    if (tid < 256 && (tid & 63) == 0) red[rr][wig] = sum;
    __syncthreads();
    float mean = (red[rr][0] + red[rr][1]) * (1.0f / 128.0f);
    float dv = val - mean;
    float sqv = dv * dv;
    for (int off = 32; off; off >>= 1) sqv += __shfl_xor(sqv, off);
    __syncthreads();
    if (tid < 256 && (tid & 63) == 0) red[rr][wig] = sqv;
    __syncthreads();
    float var = (red[rr][0] + red[rr][1]) * (1.0f / 128.0f);
    if (tid < 256) x1[rr][cc2] = dv * rsqrtf(var + 1e-5f) * g1[cc2] + b1[cc2];
    __syncthreads();
    // ---- FFN1: 1024 outputs (2 rows x 512 cols), one per thread ----
    {
        int rf = tid >> 9, cf = tid & 511;
        float s = bf1[cf];
        #pragma unroll 4
        for (int dd = 0; dd < DD; ++dd) s = fmaf(x1[rf][dd], W1[dd * DFF + cf], s);
        hhl[rf][cf] = gelu_f(s);
    }
    __syncthreads();
    // ---- FFN2 (4-way split-K over 512) ----
    {
        float p2 = 0.f;
        #pragma unroll 4
        for (int q = 0; q < 128; ++q) {
            int dd = kseg * 128 + q;
            p2 = fmaf(hhl[rr][dd], W2[dd * DD + cc2], p2);
        }
        pred4[kseg][rr][cc2] = p2;
    }
    __syncthreads();
    float val2 = pred4[0][rr][cc2] + pred4[1][rr][cc2] + pred4[2][rr][cc2] + pred4[3][rr][cc2]
               + x1[rr][cc2] + bf2[cc2];
    float sum2 = val2;
    for (int off = 32; off; off >>= 1) sum2 += __shfl_xor(sum2, off);
    if (tid < 256 && (tid & 63) == 0) red[rr][wig] = sum2;
    __syncthreads();
    float mean2 = (red[rr][0] + red[rr][1]) * (1.0f / 128.0f);
    float dv2 = val2 - mean2;
    float sq2 = dv2 * dv2;
    for (int off = 32; off; off >>= 1) sq2 += __shfl_xor(sq2, off);
    __syncthreads();
    if (tid < 256 && (tid & 63) == 0) red[rr][wig] = sq2;
    __syncthreads();
    float var2 = (red[rr][0] + red[rr][1]) * (1.0f / 128.0f);
    float outv = dv2 * rsqrtf(var2 + 1e-5f) * g2[cc2] + b2[cc2];
    if (!DO_NODE) {
        if (tid < 256) x[(r0 + rr) * DD + cc2] = outv;
        return;
    }
    // ---- fused node projections (row-local) ----
    if (tid < 256) xf[rr][cc2] = outv;
    __syncthreads();
    if (tid < 896) {
        int rl = (tid >= 448) ? 1 : 0;
        int cc = tid - rl * 448;
        int row = r0 + rl;
        const float* wp; int ldw; float bias = 0.f;
        if (cc < 64)       { wp = nodeW + cc;                     ldw = 64;  bias = nodeb[cc]; }
        else if (cc < 192) { wp = scW1 + (cc - 64);               ldw = 128; bias = scb1[cc - 64]; }
        else if (cc < 320) { wp = scW1 + 128 * 128 + (cc - 192);  ldw = 128; }
        else if (cc < 384) { wp = teW + (cc - 320);               ldw = 64;  bias = teb[cc - 320]; }
        else               { wp = teW + 128 * 64 + (cc - 384);    ldw = 64;  }
        float a = bias;
        #pragma unroll 4
        for (int dd = 0; dd < DD; ++dd) a = fmaf(xf[rl][dd], wp[dd * ldw], a);
        if (cc < 64)       out_node[row * 64 + cc] = a;
        else if (cc < 192) As[row * 128 + (cc - 64)] = a;
        else if (cc < 320) {
            int j0 = cc - 192;
            int hhi = j0 >> 6, rem = j0 & 63, jj = rem & 15, k = rem >> 4;
            Atp[row * 128 + jj * 8 + k * 2 + hhi] = a;
        }
        else if (cc < 384) Bs[row * 64 + (cc - 320)] = a;
        else {
            int jf = cc - 384, jj = jf & 15, k = jf >> 4;
            Btp[row * 64 + jj * 4 + k] = a;
        }
    }
}

// ---------------- edge kernel: 4 edges per wave (16 lanes each); gumbel + edge_index inline ----------------
__global__ __launch_bounds__(256) void k_edges(const float* __restrict__ As,
                                               const float* __restrict__ Atp,
                                               const float* __restrict__ Bs,
                                               const float* __restrict__ Btp,
                                               const float* __restrict__ scW1,
                                               const float* __restrict__ scW2,
                                               const float* __restrict__ scb2p,
                                               const float* __restrict__ teW,
                                               const float* __restrict__ u,
                                               float* __restrict__ out_feat,
                                               float* __restrict__ out_gate,
                                               float* __restrict__ out_ei) {
    int s = blockIdx.x;
    int seg = blockIdx.y;                           // 0..1
    __shared__ float lAs[128], lap[128], lw2[128], lBs[64], lbp[64];
    int tid = threadIdx.x;
    if (tid < 128) {
        lAs[tid] = As[s * 128 + tid];
        lap[tid] = scW1[256 * 128 + tid];
        lw2[tid] = scW2[tid];
    } else if (tid < 192) {
        int j = tid - 128;
        lBs[j] = Bs[s * 64 + j];
        lbp[j] = teW[256 * 64 + j];
    }
    __syncthreads();
    int w = tid >> 6, lane = tid & 63;
    int g = lane >> 4, jj = lane & 15;
    float rAs[8], rap[8], rw2[8], rBs[4], rbp[4];
    #pragma unroll
    for (int k = 0; k < 4; ++k) {
        int j = jj + 16 * k;
        rAs[2 * k] = lAs[j]; rAs[2 * k + 1] = lAs[j + 64];
        rap[2 * k] = lap[j]; rap[2 * k + 1] = lap[j + 64];
        rw2[2 * k] = lw2[j]; rw2[2 * k + 1] = lw2[j + 64];
        rBs[k] = lBs[j]; rbp[k] = lbp[j];
    }
    float scb2 = scb2p[0];
    for (int iter = 0; iter < 16; ++iter) {
        int idx = seg * 256 + w * 64 + iter * 4 + g;
        if (idx >= 511) continue;                   // uniform per 16-lane group
        int t = idx + (idx >= s);
        int e = s * 511 + idx;
        float pd = (float)(s - t) * (1.0f / 512.0f);
        const float4* ap = reinterpret_cast<const float4*>(&Atp[(size_t)t * 128 + jj * 8]);
        float4 at0 = ap[0];
        float4 at1 = ap[1];
        float part, a;
        a = fmaf(pd, rap[0], rAs[0] + at0.x); part  = fgelu(a) * rw2[0];
        a = fmaf(pd, rap[1], rAs[1] + at0.y); part += fgelu(a) * rw2[1];
        a = fmaf(pd, rap[2], rAs[2] + at0.z); part += fgelu(a) * rw2[2];
        a = fmaf(pd, rap[3], rAs[3] + at0.w); part += fgelu(a) * rw2[3];
        a = fmaf(pd, rap[4], rAs[4] + at1.x); part += fgelu(a) * rw2[4];
        a = fmaf(pd, rap[5], rAs[5] + at1.y); part += fgelu(a) * rw2[5];
        a = fmaf(pd, rap[6], rAs[6] + at1.z); part += fgelu(a) * rw2[6];
        a = fmaf(pd, rap[7], rAs[7] + at1.w); part += fgelu(a) * rw2[7];
        part += __shfl_xor(part, 1);
        part += __shfl_xor(part, 2);
        part += __shfl_xor(part, 4);
        part += __shfl_xor(part, 8);
        float logit = part + scb2;
        float uu = fminf(fmaxf(u[e], 1e-8f), 1.0f - 1e-8f);
        float nlv = -__logf(uu);                    // gate = 1/(1 + nl*exp(-logit))
        float gate = __builtin_amdgcn_rcpf(1.0f + nlv * __expf(-logit));
        float4 bt = *reinterpret_cast<const float4*>(&Btp[(size_t)t * 64 + jj * 4]);
        float f0 = fmaf(pd, rbp[0], rBs[0] + bt.x) * gate;
        float f1 = fmaf(pd, rbp[1], rBs[1] + bt.y) * gate;
        float f2 = fmaf(pd, rbp[2], rBs[2] + bt.z) * gate;
        float f3 = fmaf(pd, rbp[3], rBs[3] + bt.w) * gate;
        size_t base = (size_t)e * 64 + jj;
        out_feat[base + 0]  = f0;
        out_feat[base + 16] = f1;
        out_feat[base + 32] = f2;
        out_feat[base + 48] = f3;
        if (jj == 0) { out_gate[e] = gate; out_ei[e] = (float)s; }
        else if (jj == 1) out_ei[E_EDGES + e] = (float)t;
    }
}

extern "C" void kernel_launch(void* const* d_in, const int* in_sizes, int n_in,
                              void* d_out, int out_size, void* d_ws, size_t ws_size,
                              hipStream_t stream) {
    const int*   tok   = (const int*)d_in[0];
    const float* u     = (const float*)d_in[1];
    const float* emb   = (const float*)d_in[2];
    const float* Wqkv  = (const float*)d_in[3];
    const float* bqkv  = (const float*)d_in[4];
    const float* Wo    = (const float*)d_in[5];
    const float* bo    = (const float*)d_in[6];
    const float* ln1g  = (const float*)d_in[7];
    const float* ln1b  = (const float*)d_in[8];
    const float* Wff1  = (const float*)d_in[9];
    const float* bff1  = (const float*)d_in[10];
    const float* Wff2  = (const float*)d_in[11];
    const float* bff2  = (const float*)d_in[12];
    const float* ln2g  = (const float*)d_in[13];
    const float* ln2b  = (const float*)d_in[14];
    const float* nodeW = (const float*)d_in[15];
    const float* nodeb = (const float*)d_in[16];
    const float* scW1  = (const float*)d_in[17];
    const float* scb1  = (const float*)d_in[18];
    const float* scW2  = (const float*)d_in[19];
    const float* scb2  = (const float*)d_in[20];
    const float* teW   = (const float*)d_in[21];
    const float* teb   = (const float*)d_in[22];

    float* out      = (float*)d_out;
    float* out_node = out;                                    // [512,64]
    float* out_feat = out + 512 * 64;                         // [E,64]
    float* out_ei   = out_feat + (size_t)E_EDGES * 64;        // [2,E]
    float* out_gate = out_ei + 2 * (size_t)E_EDGES;           // [E]

    float* ws   = (float*)d_ws;
    float* x    = ws;                                         // 512*128
    float* qkv  = x + 512 * 128;                              // 512*384
    float* As   = qkv + 512 * 384;                            // 512*128
    float* Atp  = As + 512 * 128;                             // 512*128
    float* Bs   = Atp + 512 * 128;                            // 512*64
    float* Btp  = Bs + 512 * 64;                              // 512*64

    // layer 0
    k_qkv<1><<<dim3(512), dim3(384), 0, stream>>>(nullptr, tok, emb, x,
                                                  Wqkv, bqkv, qkv);
    k_attn_tail<0><<<dim3(256), dim3(1024), 0, stream>>>(qkv, x, Wo, bo,
                                                         ln1g, ln1b, Wff1, bff1, Wff2, bff2,
                                                         ln2g, ln2b,
                                                         nullptr, nullptr, nullptr, nullptr,
                                                         nullptr, nullptr,
                                                         nullptr, nullptr, nullptr, nullptr, nullptr);
    // layer 1
    k_qkv<0><<<dim3(512), dim3(384), 0, stream>>>(x, nullptr, nullptr, nullptr,
                                                  Wqkv + 128 * 384, bqkv + 384, qkv);
    k_attn_tail<1><<<dim3(256), dim3(1024), 0, stream>>>(qkv, x, Wo + 128 * 128, bo + 128,
                                                         ln1g + 128, ln1b + 128,
                                                         Wff1 + 128 * 512, bff1 + 512,
                                                         Wff2 + 512 * 128, bff2 + 128,
                                                         ln2g + 128, ln2b + 128,
                                                         nodeW, nodeb, scW1, scb1, teW, teb,
                                                         out_node, As, Atp, Bs, Btp);
    k_edges<<<dim3(512, 2), dim3(256), 0, stream>>>(As, Atp, Bs, Btp, scW1, scW2, scb2, teW, u,
                                                    out_feat, out_gate, out_ei);
}

// Round 8
// 258.716 us; speedup vs baseline: 1.0943x; 1.0885x over previous
//
#include <hip/hip_runtime.h>
#include <math.h>

#define SS 512
#define DD 128
#define HH 4
#define DHH 32
#define DFF 512
#define E_EDGES 261632   // S*S - S

// exact gelu (backbone)
__device__ __forceinline__ float gelu_f(float v) {
    return 0.5f * v * (1.0f + erff(v * 0.70710678118654752f));
}
// fast gelu (edge kernel)
__device__ __forceinline__ float fgelu(float x) {
    float x2 = x * x;
    float z = x * fmaf(-0.0713548164f, x2, -1.5957691216f);
    float e = __expf(z);
    return x * __builtin_amdgcn_rcpf(1.0f + e);
}

// ---------------- qkv projection: 1 row/block, 512 blocks (optionally fused embedding) ----------------
template<int DO_EMBED>
__global__ __launch_bounds__(384) void k_qkv(const float* __restrict__ xin,
                                             const int* __restrict__ tok,
                                             const float* __restrict__ emb,
                                             float* __restrict__ xout,
                                             const float* __restrict__ W,
                                             const float* __restrict__ b,
                                             float* __restrict__ qkv) {
    __shared__ float xs[DD];
    int row = blockIdx.x;
    int c = threadIdx.x;
    if (DO_EMBED) {
        if (c < 128) {
            float v = emb[(size_t)tok[row] * DD + c];
            int i2 = (c >> 1) << 1;
            float div = expf(-(float)i2 * (9.210340371976184f / 128.0f));
            float arg = (float)row * div;
            v += (c & 1) ? cosf(arg) : sinf(arg);
            xs[c] = v;
            xout[row * DD + c] = v;                 // residual for tail-l0
        }
    } else {
        if (c < 128) xs[c] = xin[row * DD + c];
    }
    __syncthreads();
    float a = b[c];
    #pragma unroll 4
    for (int d = 0; d < DD; ++d) a = fmaf(xs[d], W[d * 384 + c], a);
    qkv[row * 384 + c] = a;
}

// ---------------- fused attention + layer tail: 1 row/block, 1024 threads, 2 blocks/CU ----------------
template<int DO_NODE>
__global__ __launch_bounds__(1024, 8) void k_attn_tail(const float* __restrict__ qkv,
                                                       float* __restrict__ x,
                                                       const float* __restrict__ Wo,
                                                       const float* __restrict__ bo,
                                                       const float* __restrict__ g1,
                                                       const float* __restrict__ b1,
                                                       const float* __restrict__ W1,
                                                       const float* __restrict__ bf1,
                                                       const float* __restrict__ W2,
                                                       const float* __restrict__ bf2,
                                                       const float* __restrict__ g2,
                                                       const float* __restrict__ b2,
                                                       const float* __restrict__ nodeW,
                                                       const float* __restrict__ nodeb,
                                                       const float* __restrict__ scW1,
                                                       const float* __restrict__ scb1,
                                                       const float* __restrict__ teW,
                                                       const float* __restrict__ teb,
                                                       float* __restrict__ out_node,
                                                       float* __restrict__ As,
                                                       float* __restrict__ Atp,
                                                       float* __restrict__ Bs,
                                                       float* __restrict__ Btp) {
    int r = blockIdx.x;
    int tid = threadIdx.x;
    int wave = tid >> 6, lane = tid & 63;
    __shared__ float sq[DD];
    __shared__ float ps[HH][SS];                    // 8 KB
    __shared__ float smax[HH][4], ssum[HH][4];
    __shared__ float opart[HH][8][DHH];             // 4 KB
    __shared__ float os[DD];
    __shared__ float pred8[8][DD];                  // 4 KB
    __shared__ float x1s[DD];
    __shared__ float f1p[2][DFF];                   // 4 KB
    __shared__ float hhl[DFF];                      // 2 KB
    __shared__ float xf[DD];
    __shared__ float npart[2][448];                 // 3.5 KB
    __shared__ float red[2], red2[2];
    if (tid < DD) sq[tid] = qkv[r * 384 + tid];
    __syncthreads();
    // ---- QK^T: wave=(h, kq); lane: keys kq*128+lane, +64 ----
    const float scale = 0.17677669529663687f;       // 1/sqrt(32)
    int h = wave & 3, kq = wave >> 2;
    int k0 = kq * 128 + lane, k1 = k0 + 64;
    float s0 = 0.f, s1 = 0.f;
    {
        const float4* kp0 = reinterpret_cast<const float4*>(&qkv[(size_t)k0 * 384 + 128 + h * DHH]);
        const float4* kp1 = reinterpret_cast<const float4*>(&qkv[(size_t)k1 * 384 + 128 + h * DHH]);
        #pragma unroll
        for (int i = 0; i < 8; ++i) {
            float4 a = kp0[i], b4 = kp1[i];
            int d0 = h * DHH + i * 4;
            float q0 = sq[d0], q1 = sq[d0 + 1], q2 = sq[d0 + 2], q3 = sq[d0 + 3];
            s0 += a.x * q0 + a.y * q1 + a.z * q2 + a.w * q3;
            s1 += b4.x * q0 + b4.y * q1 + b4.z * q2 + b4.w * q3;
        }
        s0 *= scale; s1 *= scale;
    }
    // ---- softmax across 4 waves per head ----
    float m = fmaxf(s0, s1);
    for (int off = 32; off; off >>= 1) m = fmaxf(m, __shfl_xor(m, off));
    if (lane == 0) smax[h][kq] = m;
    __syncthreads();
    float M = fmaxf(fmaxf(smax[h][0], smax[h][1]), fmaxf(smax[h][2], smax[h][3]));
    float e0 = __expf(s0 - M), e1 = __expf(s1 - M);
    float l = e0 + e1;
    for (int off = 32; off; off >>= 1) l += __shfl_xor(l, off);
    if (lane == 0) ssum[h][kq] = l;
    __syncthreads();
    float inv = 1.0f / (ssum[h][0] + ssum[h][1] + ssum[h][2] + ssum[h][3]);
    ps[h][k0] = e0 * inv;
    ps[h][k1] = e1 * inv;
    __syncthreads();
    // ---- PV: wave=(hp, kq2); lane: d=lane&31, sub=lane>>5; 64 keys each ----
    {
        int hp = wave & 3, kq2 = wave >> 2;
        int d = lane & 31, sub = lane >> 5;
        int kb = kq2 * 128 + sub * 64;
        float acc = 0.f;
        #pragma unroll 8
        for (int i = 0; i < 64; ++i) {
            int ki = kb + i;
            acc += ps[hp][ki] * qkv[(size_t)ki * 384 + 256 + hp * DHH + d];
        }
        opart[hp][kq2 * 2 + sub][d] = acc;
    }
    __syncthreads();
    if (tid < DD) {
        int h2 = tid >> 5, dd = tid & 31;
        float o = 0.f;
        #pragma unroll
        for (int p = 0; p < 8; ++p) o += opart[h2][p][dd];
        os[tid] = o;
    }
    __syncthreads();
    // ---- proj (8-way split-K) ----
    int kseg = tid >> 7, cc = tid & 127;
    {
        float part = 0.f;
        #pragma unroll
        for (int q = 0; q < 16; ++q) {
            int dd = kseg * 16 + q;
            part = fmaf(os[dd], Wo[dd * DD + cc], part);
        }
        pred8[kseg][cc] = part;
    }
    __syncthreads();
    // ---- +residual, LN1 (threads < 128 own cols) ----
    float val = 0.f;
    if (tid < DD) {
        val = x[r * DD + tid] + bo[tid];
        #pragma unroll
        for (int p = 0; p < 8; ++p) val += pred8[p][tid];
        float sum = val;
        for (int off = 32; off; off >>= 1) sum += __shfl_xor(sum, off);
        if (lane == 0) red[wave] = sum;
    }
    __syncthreads();
    float mean = (red[0] + red[1]) * (1.0f / 128.0f);
    float dv = val - mean;
    if (tid < DD) {
        float s2 = dv * dv;
        for (int off = 32; off; off >>= 1) s2 += __shfl_xor(s2, off);
        if (lane == 0) red2[wave] = s2;
    }
    __syncthreads();
    float var = (red2[0] + red2[1]) * (1.0f / 128.0f);
    if (tid < DD) x1s[tid] = dv * rsqrtf(var + 1e-5f) * g1[tid] + b1[tid];
    __syncthreads();
    // ---- FFN1 (2-way split-K, 1024 threads) ----
    {
        int half = tid >> 9, cf = tid & 511;
        float s = 0.f;
        #pragma unroll 8
        for (int q = 0; q < 64; ++q) {
            int dd = half * 64 + q;
            s = fmaf(x1s[dd], W1[dd * DFF + cf], s);
        }
        f1p[half][cf] = s;
    }
    __syncthreads();
    if (tid < DFF) hhl[tid] = gelu_f(f1p[0][tid] + f1p[1][tid] + bf1[tid]);
    __syncthreads();
    // ---- FFN2 (8-way split-K) ----
    {
        float p2 = 0.f;
        #pragma unroll 8
        for (int q = 0; q < 64; ++q) {
            int dd = kseg * 64 + q;
            p2 = fmaf(hhl[dd], W2[dd * DD + cc], p2);
        }
        pred8[kseg][cc] = p2;
    }
    __syncthreads();
    float val2 = 0.f;
    if (tid < DD) {
        val2 = x1s[tid] + bf2[tid];
        #pragma unroll
        for (int p = 0; p < 8; ++p) val2 += pred8[p][tid];
        float sum2 = val2;
        for (int off = 32; off; off >>= 1) sum2 += __shfl_xor(sum2, off);
        if (lane == 0) red[wave] = sum2;
    }
    __syncthreads();
    float mean2 = (red[0] + red[1]) * (1.0f / 128.0f);
    float dv2 = val2 - mean2;
    if (tid < DD) {
        float s2 = dv2 * dv2;
        for (int off = 32; off; off >>= 1) s2 += __shfl_xor(s2, off);
        if (lane == 0) red2[wave] = s2;
    }
    __syncthreads();
    float var2 = (red2[0] + red2[1]) * (1.0f / 128.0f);
    float outv = dv2 * rsqrtf(var2 + 1e-5f) * g2[tid & 127] + b2[tid & 127];
    if (!DO_NODE) {
        if (tid < DD) x[r * DD + tid] = outv;
        return;
    }
    // ---- fused node projections (2-way split-K over 896 threads) ----
    if (tid < DD) xf[tid] = outv;
    __syncthreads();
    if (tid < 896) {
        int half = (tid >= 448) ? 1 : 0;
        int cc2 = tid - half * 448;
        const float* wp; int ldw;
        if (cc2 < 64)       { wp = nodeW + cc2;                     ldw = 64;  }
        else if (cc2 < 192) { wp = scW1 + (cc2 - 64);               ldw = 128; }
        else if (cc2 < 320) { wp = scW1 + 128 * 128 + (cc2 - 192);  ldw = 128; }
        else if (cc2 < 384) { wp = teW + (cc2 - 320);               ldw = 64;  }
        else                { wp = teW + 128 * 64 + (cc2 - 384);    ldw = 64;  }
        float a = 0.f;
        #pragma unroll 8
        for (int q = 0; q < 64; ++q) {
            int dd = half * 64 + q;
            a = fmaf(xf[dd], wp[dd * ldw], a);
        }
        npart[half][cc2] = a;
    }
    __syncthreads();
    if (tid < 448) {
        int cc2 = tid;
        float a = npart[0][cc2] + npart[1][cc2];
        if (cc2 < 64)       out_node[r * 64 + cc2] = a + nodeb[cc2];
        else if (cc2 < 192) As[r * 128 + (cc2 - 64)] = a + scb1[cc2 - 64];
        else if (cc2 < 320) {
            int j0 = cc2 - 192;
            int hhi = j0 >> 6, rem = j0 & 63, jj = rem & 15, k = rem >> 4;
            Atp[r * 128 + jj * 8 + k * 2 + hhi] = a;
        }
        else if (cc2 < 384) Bs[r * 64 + (cc2 - 320)] = a + teb[cc2 - 320];
        else {
            int jf = cc2 - 384, jj = jf & 15, k = jf >> 4;
            Btp[r * 64 + jj * 4 + k] = a;
        }
    }
}

// ---------------- edge kernel: 4 edges per wave (16 lanes each); gumbel + edge_index inline ----------------
__global__ __launch_bounds__(256) void k_edges(const float* __restrict__ As,
                                               const float* __restrict__ Atp,
                                               const float* __restrict__ Bs,
                                               const float* __restrict__ Btp,
                                               const float* __restrict__ scW1,
                                               const float* __restrict__ scW2,
                                               const float* __restrict__ scb2p,
                                               const float* __restrict__ teW,
                                               const float* __restrict__ u,
                                               float* __restrict__ out_feat,
                                               float* __restrict__ out_gate,
                                               float* __restrict__ out_ei) {
    int s = blockIdx.x;
    int seg = blockIdx.y;                           // 0..3
    __shared__ float lAs[128], lap[128], lw2[128], lBs[64], lbp[64];
    int tid = threadIdx.x;
    if (tid < 128) {
        lAs[tid] = As[s * 128 + tid];
        lap[tid] = scW1[256 * 128 + tid];
        lw2[tid] = scW2[tid];
    } else if (tid < 192) {
        int j = tid - 128;
        lBs[j] = Bs[s * 64 + j];
        lbp[j] = teW[256 * 64 + j];
    }
    __syncthreads();
    int w = tid >> 6, lane = tid & 63;
    int g = lane >> 4, jj = lane & 15;
    float rAs[8], rap[8], rw2[8], rBs[4], rbp[4];
    #pragma unroll
    for (int k = 0; k < 4; ++k) {
        int j = jj + 16 * k;
        rAs[2 * k] = lAs[j]; rAs[2 * k + 1] = lAs[j + 64];
        rap[2 * k] = lap[j]; rap[2 * k + 1] = lap[j + 64];
        rw2[2 * k] = lw2[j]; rw2[2 * k + 1] = lw2[j + 64];
        rBs[k] = lBs[j]; rbp[k] = lbp[j];
    }
    float scb2 = scb2p[0];
    for (int iter = 0; iter < 8; ++iter) {
        int idx = seg * 128 + iter * 16 + w * 4 + g;
        if (idx >= 511) continue;                   // uniform per 16-lane group
        int t = idx + (idx >= s);
        int e = s * 511 + idx;
        float pd = (float)(s - t) * (1.0f / 512.0f);
        const float4* ap = reinterpret_cast<const float4*>(&Atp[(size_t)t * 128 + jj * 8]);
        float4 at0 = ap[0];
        float4 at1 = ap[1];
        float part, a;
        a = fmaf(pd, rap[0], rAs[0] + at0.x); part  = fgelu(a) * rw2[0];
        a = fmaf(pd, rap[1], rAs[1] + at0.y); part += fgelu(a) * rw2[1];
        a = fmaf(pd, rap[2], rAs[2] + at0.z); part += fgelu(a) * rw2[2];
        a = fmaf(pd, rap[3], rAs[3] + at0.w); part += fgelu(a) * rw2[3];
        a = fmaf(pd, rap[4], rAs[4] + at1.x); part += fgelu(a) * rw2[4];
        a = fmaf(pd, rap[5], rAs[5] + at1.y); part += fgelu(a) * rw2[5];
        a = fmaf(pd, rap[6], rAs[6] + at1.z); part += fgelu(a) * rw2[6];
        a = fmaf(pd, rap[7], rAs[7] + at1.w); part += fgelu(a) * rw2[7];
        part += __shfl_xor(part, 1);
        part += __shfl_xor(part, 2);
        part += __shfl_xor(part, 4);
        part += __shfl_xor(part, 8);
        float logit = part + scb2;
        float uu = fminf(fmaxf(u[e], 1e-8f), 1.0f - 1e-8f);
        float nlv = -__logf(uu);                    // gate = 1/(1 + nl*exp(-logit))
        float gate = __builtin_amdgcn_rcpf(1.0f + nlv * __expf(-logit));
        float4 bt = *reinterpret_cast<const float4*>(&Btp[(size_t)t * 64 + jj * 4]);
        float f0 = fmaf(pd, rbp[0], rBs[0] + bt.x) * gate;
        float f1 = fmaf(pd, rbp[1], rBs[1] + bt.y) * gate;
        float f2 = fmaf(pd, rbp[2], rBs[2] + bt.z) * gate;
        float f3 = fmaf(pd, rbp[3], rBs[3] + bt.w) * gate;
        size_t base = (size_t)e * 64 + jj;
        out_feat[base + 0]  = f0;
        out_feat[base + 16] = f1;
        out_feat[base + 32] = f2;
        out_feat[base + 48] = f3;
        if (jj == 0) { out_gate[e] = gate; out_ei[e] = (float)s; }
        else if (jj == 1) out_ei[E_EDGES + e] = (float)t;
    }
}

extern "C" void kernel_launch(void* const* d_in, const int* in_sizes, int n_in,
                              void* d_out, int out_size, void* d_ws, size_t ws_size,
                              hipStream_t stream) {
    const int*   tok   = (const int*)d_in[0];
    const float* u     = (const float*)d_in[1];
    const float* emb   = (const float*)d_in[2];
    const float* Wqkv  = (const float*)d_in[3];
    const float* bqkv  = (const float*)d_in[4];
    const float* Wo    = (const float*)d_in[5];
    const float* bo    = (const float*)d_in[6];
    const float* ln1g  = (const float*)d_in[7];
    const float* ln1b  = (const float*)d_in[8];
    const float* Wff1  = (const float*)d_in[9];
    const float* bff1  = (const float*)d_in[10];
    const float* Wff2  = (const float*)d_in[11];
    const float* bff2  = (const float*)d_in[12];
    const float* ln2g  = (const float*)d_in[13];
    const float* ln2b  = (const float*)d_in[14];
    const float* nodeW = (const float*)d_in[15];
    const float* nodeb = (const float*)d_in[16];
    const float* scW1  = (const float*)d_in[17];
    const float* scb1  = (const float*)d_in[18];
    const float* scW2  = (const float*)d_in[19];
    const float* scb2  = (const float*)d_in[20];
    const float* teW   = (const float*)d_in[21];
    const float* teb   = (const float*)d_in[22];

    float* out      = (float*)d_out;
    float* out_node = out;                                    // [512,64]
    float* out_feat = out + 512 * 64;                         // [E,64]
    float* out_ei   = out_feat + (size_t)E_EDGES * 64;        // [2,E]
    float* out_gate = out_ei + 2 * (size_t)E_EDGES;           // [E]

    float* ws   = (float*)d_ws;
    float* x    = ws;                                         // 512*128
    float* qkv  = x + 512 * 128;                              // 512*384
    float* As   = qkv + 512 * 384;                            // 512*128
    float* Atp  = As + 512 * 128;                             // 512*128
    float* Bs   = Atp + 512 * 128;                            // 512*64
    float* Btp  = Bs + 512 * 64;                              // 512*64

    // layer 0
    k_qkv<1><<<dim3(512), dim3(384), 0, stream>>>(nullptr, tok, emb, x,
                                                  Wqkv, bqkv, qkv);
    k_attn_tail<0><<<dim3(512), dim3(1024), 0, stream>>>(qkv, x, Wo, bo,
                                                         ln1g, ln1b, Wff1, bff1, Wff2, bff2,
                                                         ln2g, ln2b,
                                                         nullptr, nullptr, nullptr, nullptr,
                                                         nullptr, nullptr,
                                                         nullptr, nullptr, nullptr, nullptr, nullptr);
    // layer 1
    k_qkv<0><<<dim3(512), dim3(384), 0, stream>>>(x, nullptr, nullptr, nullptr,
                                                  Wqkv + 128 * 384, bqkv + 384, qkv);
    k_attn_tail<1><<<dim3(512), dim3(1024), 0, stream>>>(qkv, x, Wo + 128 * 128, bo + 128,
                                                         ln1g + 128, ln1b + 128,
                                                         Wff1 + 128 * 512, bff1 + 512,
                                                         Wff2 + 512 * 128, bff2 + 128,
                                                         ln2g + 128, ln2b + 128,
                                                         nodeW, nodeb, scW1, scb1, teW, teb,
                                                         out_node, As, Atp, Bs, Btp);
    k_edges<<<dim3(512, 4), dim3(256), 0, stream>>>(As, Atp, Bs, Btp, scW1, scW2, scb2, teW, u,
                                                    out_feat, out_gate, out_ei);
}